// Round 1
// baseline (5701.966 us; speedup 1.0000x reference)
//
#include <hip/hip_runtime.h>

// ODE-GRU recurrence, B=128, L=2048, I=D=64.
// R6: multi-batch latency amortization. The recurrence step has a fixed
// ~1400-cycle serial cost (2 barriers + 2 LDS round trips + dep chains) that
// dominated at 1 batch/block (step ~1935 cy, VALU only ~535 cy). Weights are
// batch-invariant and register-resident, so each block now carries G=4
// independent batches: per step, each thread runs its round-1/round-2 dots for
// all 4 h-vectors between the SAME two barriers. The 4 streams are independent
// -> their chains pipeline, paying the fixed latency once per step instead of
// once per batch-step. TILE shrunk 32->8 so 4x LDS tiles fit (43 KB static).
//
// Carried from R5: octet-per-element layout (element q owned by lanes
// 8q..8q+7; quad A = +0..3, quad B = +4..7), 2 barriers/step, gh linearity
// (M2 = Whh@dw2, c2 = Whh@db2 prepped into d_ws), packed-fp32 dots, DPP quad
// butterflies, DPP octet swap for n (no LDS), gx tile precompute, LDS-buffered
// output flush.

#define NB    128
#define SEQ   2048
#define DIM   64
#define TILE  8      // timesteps per tile (was 32; shrunk for G=4 LDS budget)
#define G     4      // batches per block
#define XS    68     // sh_x row stride (floats)
#define GS    196    // sh_gx row stride (floats)

typedef float f32x2 __attribute__((ext_vector_type(2)));

__device__ __forceinline__ float fast_rcp(float x) { return __builtin_amdgcn_rcpf(x); }

__device__ __forceinline__ float sigmoid_f(float v) {
    return fast_rcp(1.0f + __expf(-v));
}
__device__ __forceinline__ float tanh_f(float v) {
    float e = __expf(2.0f * v);
    return fmaf(-2.0f, fast_rcp(e + 1.0f), 1.0f);
}

// Butterfly sum over a lane-quad; every lane of the quad gets the total.
__device__ __forceinline__ float quad_reduce(float v) {
    v += __int_as_float(__builtin_amdgcn_mov_dpp(__float_as_int(v), 0xB1, 0xF, 0xF, true));
    v += __int_as_float(__builtin_amdgcn_mov_dpp(__float_as_int(v), 0x4E, 0xF, 0xF, true));
    return v;
}

// Swap values between the two quads of each 8-lane octet (row_half_mirror).
__device__ __forceinline__ float octet_swap(float v) {
    return __int_as_float(__builtin_amdgcn_mov_dpp(__float_as_int(v), 0x141, 0xF, 0xF, true));
}

// 16-element dot in packed fp32: 8 v_pk_fma_f32 + pk_add + add.
__device__ __forceinline__ float dot16p(const float4* w, const float4* h) {
    f32x2 a; a.x = 0.f; a.y = 0.f;
    f32x2 b; b.x = 0.f; b.y = 0.f;
#pragma unroll
    for (int i = 0; i < 4; i++) {
        f32x2 wlo; wlo.x = w[i].x; wlo.y = w[i].y;
        f32x2 whi; whi.x = w[i].z; whi.y = w[i].w;
        f32x2 hlo; hlo.x = h[i].x; hlo.y = h[i].y;
        f32x2 hhi; hhi.x = h[i].z; hhi.y = h[i].w;
        a = __builtin_elementwise_fma(wlo, hlo, a);
        b = __builtin_elementwise_fma(whi, hhi, b);
    }
    f32x2 s = a + b;
    return s.x + s.y;
}

// ---- prep: M2 = Whh @ dw2 (192x64), c2 = Whh @ db2 (192) ----
__global__ void odegru_prep(const float* __restrict__ w_hh,
                            const float* __restrict__ dw2,
                            const float* __restrict__ db2,
                            float* __restrict__ m2,   // 192*64
                            float* __restrict__ c2)   // 192
{
    const int idx = blockIdx.x * 256 + threadIdx.x;
    if (idx < 192 * 64) {
        const int r = idx >> 6, k = idx & 63;
        float s = 0.f;
#pragma unroll
        for (int j = 0; j < 64; j++) s = fmaf(w_hh[r * 64 + j], dw2[j * 64 + k], s);
        m2[idx] = s;
    }
    if (idx < 192) {
        float s = 0.f;
#pragma unroll
        for (int j = 0; j < 64; j++) s = fmaf(w_hh[idx * 64 + j], db2[j], s);
        c2[idx] = s;
    }
}

__global__ __launch_bounds__(512, 2)
void odegru_fused(const float* __restrict__ x,        // (B,L,I)
                  const float* __restrict__ tds,      // (B,L)
                  const int*   __restrict__ seq_lens, // (B)
                  const float* __restrict__ h0,       // (D)
                  const float* __restrict__ w_ih,     // (3D,I)
                  const float* __restrict__ w_hh,     // (3D,D)
                  const float* __restrict__ b_ih,     // (3D)
                  const float* __restrict__ b_hh,     // (3D)
                  const float* __restrict__ dw1,      // (D,D)
                  const float* __restrict__ db1,      // (D)
                  const float* __restrict__ dw2,      // (D,D)
                  const float* __restrict__ db2,      // (D)
                  const float* __restrict__ m2,       // (3D,D) = Whh@dw2
                  const float* __restrict__ c2,       // (3D)   = Whh@db2
                  float* __restrict__ out)            // (B,L,D) ++ (B,D)
{
    const int b0  = blockIdx.x * G;
    const int tid = threadIdx.x;
    const int q8  = tid >> 3;         // octet = element 0..63
    const int p   = tid & 3;          // K-chunk within quad: [16p,16p+16)
    const bool qb = (tid & 4) != 0;   // quad B of the octet

    int sl[G];
#pragma unroll
    for (int g = 0; g < G; g++) sl[g] = seq_lens[b0 + g];

    __shared__ float sh_h [G][DIM];
    __shared__ float sh_t1[G][DIM];
    __shared__ float sh_x [G][TILE][XS];
    __shared__ float sh_gx[G][TILE][GS];
    __shared__ float sh_dt[G][TILE];
    __shared__ float sh_out[G][TILE][DIM];

    // ---- persistent weights: 4 dot-rows (64 floats) + 3 gx-rows (48) ----
    // Shared across all G batches — this is what makes multi-batch cheap.
    float4 wA[4], wB[4], wC[4], wD[4], wi0[4], wi1[4], wi2[4];
    {
        const float4* dw1v = (const float4*)dw1;
        const float4* dw2v = (const float4*)dw2;
        const float4* whhv = (const float4*)w_hh;
        const float4* m2v  = (const float4*)m2;
        const float4* wihv = (const float4*)w_ih;
        const int c4 = p * 4;
        if (!qb) {
#pragma unroll
            for (int i = 0; i < 4; i++) {
                wA[i] = dw1v[q8 * 16 + c4 + i];            // u    = dw1_q @ h
                wB[i] = whhv[(64 + q8) * 16 + c4 + i];     // G1   = Whh_{64+q} @ h
                wC[i] = m2v [(64 + q8) * 16 + c4 + i];     // m1   = M2_{64+q} @ t1
                wD[i] = dw2v[q8 * 16 + c4 + i];            // hot  = dw2_q @ t1
            }
        } else {
#pragma unroll
            for (int i = 0; i < 4; i++) {
                wA[i] = whhv[q8 * 16 + c4 + i];            // G0   = Whh_q @ h
                wB[i] = whhv[(128 + q8) * 16 + c4 + i];    // G2   = Whh_{128+q} @ h
                wC[i] = m2v [q8 * 16 + c4 + i];            // m0   = M2_q @ t1
                wD[i] = m2v [(128 + q8) * 16 + c4 + i];    // m2   = M2_{128+q} @ t1
            }
        }
        // gx precompute rows (quad qg = (tid>>2)&63)
        const int qg = (tid >> 2) & 63;
#pragma unroll
        for (int i = 0; i < 4; i++) {
            wi0[i] = wihv[(qg)       * 16 + c4 + i];
            wi1[i] = wihv[(64 + qg)  * 16 + c4 + i];
            wi2[i] = wihv[(128 + qg) * 16 + c4 + i];
        }
    }
    // biases: quad A: {db1_q, bh1, c1, db2_q}; quad B: {bh0, c0, bh2, c2n}
    float fA, fB, fC, fD;
    if (!qb) { fA = db1[q8];      fB = b_hh[64 + q8];  fC = c2[64 + q8];    fD = db2[q8]; }
    else     { fA = b_hh[q8];     fB = c2[q8];         fC = b_hh[128 + q8]; fD = c2[128 + q8]; }
    const int qg = (tid >> 2) & 63;
    const float rbx0 = b_ih[qg], rbx1 = b_ih[64 + qg], rbx2 = b_ih[128 + qg];

    if (tid < DIM) {
#pragma unroll
        for (int g = 0; g < G; g++) sh_h[g][tid] = h0[tid];
    }

    for (int t0 = 0; t0 < SEQ; t0 += TILE) {
        // ---- stage x tiles (masked) + dt tiles (masked); 512 f4 = 1/thread ----
        {
            const int gs  = tid >> 7;        // batch this thread stages
            const int idx = tid & 127;       // f4 index within the batch tile
            const int ts0 = idx >> 4, j = idx & 15;
            const float4* src = (const float4*)(x + ((size_t)(b0 + gs) * SEQ + t0) * DIM);
            float4 v = src[idx];
            if (t0 + ts0 >= sl[gs]) v = make_float4(0.f, 0.f, 0.f, 0.f);
            *(float4*)&sh_x[gs][ts0][4 * j] = v;
            if (tid < G * TILE) {
                const int gd = tid >> 3, ts = tid & (TILE - 1);
                const int t = t0 + ts;
                sh_dt[gd][ts] = (t < sl[gd]) ? tds[(size_t)(b0 + gd) * SEQ + t] : 0.0f;
            }
        }
        __syncthreads();

        // ---- gx tiles: rows {qg,64+qg,128+qg}; 32 (g,ts) combos, halves split even/odd ----
        {
            const int c4 = p * 4;
            const int half = (tid >= 256) ? 1 : 0;
            for (int cc = half; cc < G * TILE; cc += 2) {
                const int gg = cc >> 3, ts = cc & (TILE - 1);
                const float4* xv = (const float4*)&sh_x[gg][ts][0];
                float4 x4[4] = { xv[c4], xv[c4 + 1], xv[c4 + 2], xv[c4 + 3] };
                float A0 = quad_reduce(dot16p(wi0, x4));
                float A1 = quad_reduce(dot16p(wi1, x4));
                float A2 = quad_reduce(dot16p(wi2, x4));
                if (p == 0) {
                    sh_gx[gg][ts][qg]       = A0 + rbx0;
                    sh_gx[gg][ts][64 + qg]  = A1 + rbx1;
                    sh_gx[gg][ts][128 + qg] = A2 + rbx2;
                }
            }
        }
        __syncthreads();

#pragma unroll 1
        for (int ts = 0; ts < TILE; ts++) {
            const int t = t0 + ts;

            // ---- prefetch (independent LDS reads, all G batches) ----
            float dtv[G], gA[G], gB[G], hq[G];
#pragma unroll
            for (int g = 0; g < G; g++) {
                dtv[g] = sh_dt[g][ts];
                gB[g] = 0.f; hq[g] = 0.f;
                if (!qb) { gA[g] = sh_gx[g][ts][64 + q8]; hq[g] = sh_h[g][q8]; }       // gx1
                else     { gA[g] = sh_gx[g][ts][q8];      gB[g] = sh_gx[g][ts][128 + q8]; } // gx0, gx2
            }

            // ---- Round 1 (read h): 2 dots/lane/batch; 4 independent streams ----
            float sA[G], sB[G];
#pragma unroll
            for (int g = 0; g < G; g++) {
                const float4* hv = (const float4*)sh_h[g];
                float4 h4[4] = { hv[4 * p], hv[4 * p + 1], hv[4 * p + 2], hv[4 * p + 3] };
                sA[g] = quad_reduce(dot16p(wA, h4));  // A: u   | B: G0
                sB[g] = quad_reduce(dot16p(wB, h4));  // A: G1  | B: G2
            }
            if (!qb) {
#pragma unroll
                for (int g = 0; g < G; g++) {
                    const float t1v = tanh_f(sA[g] + fA);
                    if (p == 0) sh_t1[g][q8] = t1v;
                }
            }
            __syncthreads();   // t1 visible

            // ---- Round 2 (read t1): 2 dots/lane/batch + finish ----
#pragma unroll
            for (int g = 0; g < G; g++) {
                const float4* tv = (const float4*)sh_t1[g];
                float4 t4[4] = { tv[4 * p], tv[4 * p + 1], tv[4 * p + 2], tv[4 * p + 3] };
                const float sC = quad_reduce(dot16p(wC, t4));  // A: m1  | B: m0
                const float sD = quad_reduce(dot16p(wD, t4));  // A: hot | B: m2
                float val, z = 0.f, ho = 0.f;
                if (!qb) {
                    z   = sigmoid_f(gA[g] + sB[g] + fmaf(dtv[g], sC + fC, fB));  // z-gate
                    ho  = fmaf(dtv[g], sD + fD, hq[g]);                          // h_ode
                    val = 0.f;
                } else {
                    const float r   = sigmoid_f(gA[g] + sA[g] + fmaf(dtv[g], sC + fB, fA));
                    const float ghn = sB[g] + fmaf(dtv[g], sD + fD, fC);
                    val = tanh_f(fmaf(r, ghn, gB[g]));                           // n
                }
                const float n = octet_swap(val);   // quad A receives n from quad B
                if (!qb) {
                    const float hn = fmaf(z, ho - n, n);   // (1-z)*n + z*ho
                    if (p == 0) {
                        sh_h[g][q8] = hn;
                        sh_out[g][ts][q8] = hn;
                        if (t == sl[g] - 1)
                            out[(size_t)NB * SEQ * DIM + (size_t)(b0 + g) * DIM + q8] = hn;
                    }
                }
            }
            __syncthreads();   // h visible
        }

        // ---- flush output tiles: 512 float4 = 1/thread ----
        {
            const int gs  = tid >> 7;
            const int idx = tid & 127;
            float4* dst = (float4*)(out + ((size_t)(b0 + gs) * SEQ + t0) * DIM);
            const float4* srcv = (const float4*)(&sh_out[gs][0][0]);
            dst[idx] = srcv[idx];
        }
    }
}

extern "C" void kernel_launch(void* const* d_in, const int* in_sizes, int n_in,
                              void* d_out, int out_size, void* d_ws, size_t ws_size,
                              hipStream_t stream) {
    const float* x    = (const float*)d_in[0];
    const float* tds  = (const float*)d_in[1];
    const int*   sl   = (const int*)  d_in[2];
    const float* h0   = (const float*)d_in[3];
    const float* w_ih = (const float*)d_in[4];
    const float* w_hh = (const float*)d_in[5];
    const float* b_ih = (const float*)d_in[6];
    const float* b_hh = (const float*)d_in[7];
    const float* dw1  = (const float*)d_in[8];
    const float* db1  = (const float*)d_in[9];
    const float* dw2  = (const float*)d_in[10];
    const float* db2  = (const float*)d_in[11];
    float* out = (float*)d_out;

    float* m2 = (float*)d_ws;              // 192*64 floats
    float* c2 = m2 + 192 * 64;             // 192 floats

    odegru_prep<<<dim3(48), dim3(256), 0, stream>>>(w_hh, dw2, db2, m2, c2);
    odegru_fused<<<dim3(NB / G), dim3(512), 0, stream>>>(
        x, tds, sl, h0, w_ih, w_hh, b_ih, b_hh, dw1, db1, dw2, db2, m2, c2, out);
}

// Round 3
// 2291.472 us; speedup vs baseline: 2.4883x; 2.4883x over previous
//
#include <hip/hip_runtime.h>

// ODE-GRU recurrence, B=128, L=2048, I=D=64.
// R7b: same work, twice the waves (R7 with the DPP ctrl as a template arg —
// __builtin_amdgcn_mov_dpp requires an ICE). R6 post-mortem: wall time =
// per-block time (batches already parallel across blocks), and R5's step =
// ~1050 cy VALU issue + ~880 cy stall per SIMD with only 2 lockstep
// waves/SIMD. R7 keeps one batch per block but re-partitions the SAME work
// over 1024 threads (16 waves, 4/SIMD): per-wave chains halve (dot8, 4-FMA
// chains), and 4 waves/SIMD hide the LDS/barrier latency that 2 could not.
//   Element q owned by 16-lane hex (lanes 16q..16q+15); halves A (lanes+0..7)
//   and B (+8..15) take R5's quad-A/quad-B roles; K-chunk [8p,8p+8) per lane.
//   Octet reduce = DPP xor1(0xB1)+xor2(0x4E)+half_mirror(0x141);
//   n moves B->A via one DPP row_mirror (0x140) across the hex.
// Carried from R5: 2 barriers/step (algebraic minimum), gh linearity
// (M2=Whh@dw2, c2=Whh@db2 prepped in d_ws), packed-fp32 dots, gx tile
// precompute (now 8-lane groups), LDS-buffered output flush, TILE=32.

#define NB    128
#define SEQ   2048
#define DIM   64
#define TILE  32
#define XS    68     // sh_x row stride (floats)
#define GS    200    // sh_gx row stride (floats)

typedef float f32x2 __attribute__((ext_vector_type(2)));

__device__ __forceinline__ float fast_rcp(float x) { return __builtin_amdgcn_rcpf(x); }

__device__ __forceinline__ float sigmoid_f(float v) {
    return fast_rcp(1.0f + __expf(-v));
}
__device__ __forceinline__ float tanh_f(float v) {
    float e = __expf(2.0f * v);
    return fmaf(-2.0f, fast_rcp(e + 1.0f), 1.0f);
}

template <int CTRL>
__device__ __forceinline__ float dpp_f(float v) {
    return __int_as_float(__builtin_amdgcn_mov_dpp(__float_as_int(v), CTRL, 0xF, 0xF, true));
}

// Butterfly sum over an 8-lane octet; every lane of the octet gets the total.
// Stages: xor1 (quad_perm [1,0,3,2]), xor2 (quad_perm [2,3,0,1]),
// then merge quads via row_half_mirror (lane p <- 7-p within each 8).
__device__ __forceinline__ float oct_reduce(float v) {
    v += dpp_f<0xB1>(v);
    v += dpp_f<0x4E>(v);
    v += dpp_f<0x141>(v);
    return v;
}

// Mirror across the 16-lane DPP row: lane i <- lane 15-i. Half A of a hex
// receives half B's (uniform) value.
__device__ __forceinline__ float hex_mirror(float v) {
    return dpp_f<0x140>(v);
}

// 8-element dot in packed fp32: 4 v_pk_fma_f32 + pk_add + add.
__device__ __forceinline__ float dot8p(const float4* w, const float4* h) {
    f32x2 a; a.x = 0.f; a.y = 0.f;
    f32x2 b; b.x = 0.f; b.y = 0.f;
#pragma unroll
    for (int i = 0; i < 2; i++) {
        f32x2 wlo; wlo.x = w[i].x; wlo.y = w[i].y;
        f32x2 whi; whi.x = w[i].z; whi.y = w[i].w;
        f32x2 hlo; hlo.x = h[i].x; hlo.y = h[i].y;
        f32x2 hhi; hhi.x = h[i].z; hhi.y = h[i].w;
        a = __builtin_elementwise_fma(wlo, hlo, a);
        b = __builtin_elementwise_fma(whi, hhi, b);
    }
    f32x2 s = a + b;
    return s.x + s.y;
}

// ---- prep: M2 = Whh @ dw2 (192x64), c2 = Whh @ db2 (192) ----
__global__ void odegru_prep(const float* __restrict__ w_hh,
                            const float* __restrict__ dw2,
                            const float* __restrict__ db2,
                            float* __restrict__ m2,   // 192*64
                            float* __restrict__ c2)   // 192
{
    const int idx = blockIdx.x * 256 + threadIdx.x;
    if (idx < 192 * 64) {
        const int r = idx >> 6, k = idx & 63;
        float s = 0.f;
#pragma unroll
        for (int j = 0; j < 64; j++) s = fmaf(w_hh[r * 64 + j], dw2[j * 64 + k], s);
        m2[idx] = s;
    }
    if (idx < 192) {
        float s = 0.f;
#pragma unroll
        for (int j = 0; j < 64; j++) s = fmaf(w_hh[idx * 64 + j], db2[j], s);
        c2[idx] = s;
    }
}

__global__ __launch_bounds__(1024, 4)
void odegru_fused(const float* __restrict__ x,        // (B,L,I)
                  const float* __restrict__ tds,      // (B,L)
                  const int*   __restrict__ seq_lens, // (B)
                  const float* __restrict__ h0,       // (D)
                  const float* __restrict__ w_ih,     // (3D,I)
                  const float* __restrict__ w_hh,     // (3D,D)
                  const float* __restrict__ b_ih,     // (3D)
                  const float* __restrict__ b_hh,     // (3D)
                  const float* __restrict__ dw1,      // (D,D)
                  const float* __restrict__ db1,      // (D)
                  const float* __restrict__ dw2,      // (D,D)
                  const float* __restrict__ db2,      // (D)
                  const float* __restrict__ m2,       // (3D,D) = Whh@dw2
                  const float* __restrict__ c2,       // (3D)   = Whh@db2
                  float* __restrict__ out)            // (B,L,D) ++ (B,D)
{
    const int b   = blockIdx.x;
    const int tid = threadIdx.x;
    const int q16 = tid >> 4;         // hex = element 0..63
    const int p   = tid & 7;          // K-chunk within half: [8p, 8p+8)
    const bool hb = (tid & 8) != 0;   // half B of the hex
    const int seqlen = seq_lens[b];

    __shared__ float sh_h [DIM];
    __shared__ float sh_t1[DIM];
    __shared__ float sh_x [TILE][XS];
    __shared__ float sh_gx[TILE][GS];
    __shared__ float sh_dt[TILE];
    __shared__ float sh_out[TILE][DIM];

    // ---- persistent weights: 4 dot-rows (8 floats each) + 3 gx-rows ----
    float4 wA[2], wB[2], wC[2], wD[2], wi0[2], wi1[2], wi2[2];
    {
        const float4* dw1v = (const float4*)dw1;
        const float4* dw2v = (const float4*)dw2;
        const float4* whhv = (const float4*)w_hh;
        const float4* m2v  = (const float4*)m2;
        const float4* wihv = (const float4*)w_ih;
        const int c2i = p * 2;
        if (!hb) {
#pragma unroll
            for (int i = 0; i < 2; i++) {
                wA[i] = dw1v[q16 * 16 + c2i + i];            // u    = dw1_q @ h
                wB[i] = whhv[(64 + q16) * 16 + c2i + i];     // G1   = Whh_{64+q} @ h
                wC[i] = m2v [(64 + q16) * 16 + c2i + i];     // m1   = M2_{64+q} @ t1
                wD[i] = dw2v[q16 * 16 + c2i + i];            // hot  = dw2_q @ t1
            }
        } else {
#pragma unroll
            for (int i = 0; i < 2; i++) {
                wA[i] = whhv[q16 * 16 + c2i + i];            // G0   = Whh_q @ h
                wB[i] = whhv[(128 + q16) * 16 + c2i + i];    // G2   = Whh_{128+q} @ h
                wC[i] = m2v [q16 * 16 + c2i + i];            // m0   = M2_q @ t1
                wD[i] = m2v [(128 + q16) * 16 + c2i + i];    // m2   = M2_{128+q} @ t1
            }
        }
        // gx precompute rows: 8-lane group qg = (tid>>3)&63
        const int qg = (tid >> 3) & 63;
#pragma unroll
        for (int i = 0; i < 2; i++) {
            wi0[i] = wihv[(qg)       * 16 + c2i + i];
            wi1[i] = wihv[(64 + qg)  * 16 + c2i + i];
            wi2[i] = wihv[(128 + qg) * 16 + c2i + i];
        }
    }
    // biases: half A: {db1_q, bh1, c1, db2_q}; half B: {bh0, c0, bh2, c2n}
    float fA, fB, fC, fD;
    if (!hb) { fA = db1[q16];      fB = b_hh[64 + q16];  fC = c2[64 + q16];    fD = db2[q16]; }
    else     { fA = b_hh[q16];     fB = c2[q16];         fC = b_hh[128 + q16]; fD = c2[128 + q16]; }
    const int qg = (tid >> 3) & 63;
    const float rbx0 = b_ih[qg], rbx1 = b_ih[64 + qg], rbx2 = b_ih[128 + qg];

    if (tid < DIM) sh_h[tid] = h0[tid];

    const float* xb  = x   + (size_t)b * SEQ * DIM;
    const float* tdb = tds + (size_t)b * SEQ;
    float* outb = out + (size_t)b * SEQ * DIM;
    float* finb = out + (size_t)NB * SEQ * DIM + (size_t)b * DIM;

    for (int t0 = 0; t0 < SEQ; t0 += TILE) {
        // ---- stage x tile (masked) + dt tile (masked); 512 f4, tid<512 ----
        {
            if (tid < 512) {
                const float4* src = (const float4*)(xb + (size_t)t0 * DIM);
                const int ts0 = tid >> 4, j = tid & 15;
                float4 v = src[tid];
                if (t0 + ts0 >= seqlen) v = make_float4(0.f, 0.f, 0.f, 0.f);
                *(float4*)&sh_x[ts0][4 * j] = v;
            }
            if (tid < TILE) {
                const int t = t0 + tid;
                sh_dt[tid] = (t < seqlen) ? tdb[t] : 0.0f;
            }
        }
        __syncthreads();

        // ---- gx tile: 8-lane groups, rows {qg,64+qg,128+qg}; 2-way ts split ----
        {
            const int c2i = p * 2;
            const int set = tid >> 9;   // 0 or 1
            for (int ts = set; ts < TILE; ts += 2) {
                const float4* xv = (const float4*)&sh_x[ts][0];
                float4 x4[2] = { xv[c2i], xv[c2i + 1] };
                float A0 = oct_reduce(dot8p(wi0, x4));
                float A1 = oct_reduce(dot8p(wi1, x4));
                float A2 = oct_reduce(dot8p(wi2, x4));
                if (p == 0) {
                    sh_gx[ts][qg]       = A0 + rbx0;
                    sh_gx[ts][64 + qg]  = A1 + rbx1;
                    sh_gx[ts][128 + qg] = A2 + rbx2;
                }
            }
        }
        __syncthreads();

#pragma unroll 1
        for (int ts = 0; ts < TILE; ts++) {
            const int t = t0 + ts;

            // ---- prefetch (independent LDS reads) ----
            const float dtv = sh_dt[ts];
            float gA, gB = 0.f, hq = 0.f;
            if (!hb) { gA = sh_gx[ts][64 + q16]; hq = sh_h[q16]; }        // gx1
            else     { gA = sh_gx[ts][q16];      gB = sh_gx[ts][128 + q16]; } // gx0, gx2

            // ---- Round 1 (read h): 2 dot8/lane ----
            const float4* hv = (const float4*)sh_h;
            float4 h4[2] = { hv[2 * p], hv[2 * p + 1] };
            const float sA = oct_reduce(dot8p(wA, h4));  // A: u   | B: G0
            const float sB = oct_reduce(dot8p(wB, h4));  // A: G1  | B: G2
            if (!hb) {
                const float t1v = tanh_f(sA + fA);
                if (p == 0) sh_t1[q16] = t1v;
            }
            __syncthreads();   // t1 visible

            // ---- Round 2 (read t1): 2 dot8/lane + finish ----
            const float4* tv = (const float4*)sh_t1;
            float4 t4[2] = { tv[2 * p], tv[2 * p + 1] };
            const float sC = oct_reduce(dot8p(wC, t4));  // A: m1  | B: m0
            const float sD = oct_reduce(dot8p(wD, t4));  // A: hot | B: m2
            float val, z = 0.f, ho = 0.f;
            if (!hb) {
                z   = sigmoid_f(gA + sB + fmaf(dtv, sC + fC, fB));     // z-gate
                ho  = fmaf(dtv, sD + fD, hq);                          // h_ode
                val = 0.f;
            } else {
                const float r   = sigmoid_f(gA + sA + fmaf(dtv, sC + fB, fA));
                const float ghn = sB + fmaf(dtv, sD + fD, fC);
                val = tanh_f(fmaf(r, ghn, gB));                        // n
            }
            const float n = hex_mirror(val);   // half A receives n from half B
            if (!hb) {
                const float hn = fmaf(z, ho - n, n);   // (1-z)*n + z*ho
                if (p == 0) {
                    sh_h[q16] = hn;
                    sh_out[ts][q16] = hn;
                    if (t == seqlen - 1) finb[q16] = hn;
                }
            }
            __syncthreads();   // h visible
        }

        // ---- flush output tile: 512 float4, tid<512 ----
        if (tid < 512) {
            float4* dst = (float4*)(outb + (size_t)t0 * DIM);
            const float4* srcv = (const float4*)(&sh_out[0][0]);
            dst[tid] = srcv[tid];
        }
        __syncthreads();
    }
}

extern "C" void kernel_launch(void* const* d_in, const int* in_sizes, int n_in,
                              void* d_out, int out_size, void* d_ws, size_t ws_size,
                              hipStream_t stream) {
    const float* x    = (const float*)d_in[0];
    const float* tds  = (const float*)d_in[1];
    const int*   sl   = (const int*)  d_in[2];
    const float* h0   = (const float*)d_in[3];
    const float* w_ih = (const float*)d_in[4];
    const float* w_hh = (const float*)d_in[5];
    const float* b_ih = (const float*)d_in[6];
    const float* b_hh = (const float*)d_in[7];
    const float* dw1  = (const float*)d_in[8];
    const float* db1  = (const float*)d_in[9];
    const float* dw2  = (const float*)d_in[10];
    const float* db2  = (const float*)d_in[11];
    float* out = (float*)d_out;

    float* m2 = (float*)d_ws;              // 192*64 floats
    float* c2 = m2 + 192 * 64;             // 192 floats

    odegru_prep<<<dim3(48), dim3(256), 0, stream>>>(w_hh, dw2, db2, m2, c2);
    odegru_fused<<<dim3(NB), dim3(1024), 0, stream>>>(
        x, tds, sl, h0, w_ih, w_hh, b_ih, b_hh, dw1, db1, dw2, db2, m2, c2, out);
}